// Round 8
// baseline (250.753 us; speedup 1.0000x reference)
//
#include <hip/hip_runtime.h>
#include <hip/hip_bf16.h>
#include <cstdint>

constexpr int Bc = 2, Sc = 2048, Dc = 1024, Hc = 16;
constexpr int Mtok = Bc * Sc;  // 4096 token rows

typedef __bf16 bf16;
typedef __bf16 bf16x4 __attribute__((ext_vector_type(4)));
typedef __bf16 bf16x8 __attribute__((ext_vector_type(8)));
typedef float  f32x4  __attribute__((ext_vector_type(4)));

// async global->LDS, 16B per lane; LDS dest = wave-uniform base + lane*16
__device__ __forceinline__ void gld_lds16(const bf16* g, bf16* l) {
  __builtin_amdgcn_global_load_lds(
      (__attribute__((address_space(1))) void*)(void*)g,
      (__attribute__((address_space(3))) void*)l, 16, 0, 0);
}

// ---------------------------------------------------------------------------
// Stage a 128x64 fp32 tile -> bf16 into XOR-swizzled LDS (row stride 64 elems
// = 128 B). Thread t owns PHYSICAL chunk t&7 (all 8 bank groups covered per
// ds_write_b128 -> 2 lanes/bank = free), rows (t>>3)+32j. Physical chunk p at
// row r holds logical chunk p^(r&7); (r&7) == (t>>3)&7 for all j, so the
// logical source column is constant per thread. Reader pattern identical to
// the R6/R7 global_load_lds layout.
// ---------------------------------------------------------------------------
__device__ __forceinline__ void stage_f32_128x64(
    const float* __restrict__ g, int ldg, bf16* __restrict__ lds, int tid)
{
  const int sc  = tid & 7;                       // physical chunk
  const int sr0 = tid >> 3;                      // base row 0..31
  const int lc  = (sc ^ (sr0 & 7)) * 8;          // logical col (elems)
#pragma unroll
  for (int j = 0; j < 4; ++j) {
    const int r = sr0 + 32 * j;
    const float* s = g + (size_t)r * ldg + lc;
    f32x4 a = ((const f32x4*)s)[0], b = ((const f32x4*)s)[1];
    bf16x8 t;
    t[0]=(bf16)a[0]; t[1]=(bf16)a[1]; t[2]=(bf16)a[2]; t[3]=(bf16)a[3];
    t[4]=(bf16)b[0]; t[5]=(bf16)b[1]; t[6]=(bf16)b[2]; t[7]=(bf16)b[3];
    *(bf16x8*)&lds[r * 64 + sc * 8] = t;
  }
}

// ---------------------------------------------------------------------------
// Fused Q/K/V projection GEMM, fp32-direct: 128x128 tile, BK=64, XOR-swizzled
// LDS, A and B staged from fp32 with in-staging bf16 conversion (convert_all
// kernel eliminated). grid (32,8,3).
// z==2 (V) writes output TRANSPOSED to Vt (B, D, S) with packed 8B stores.
// ---------------------------------------------------------------------------
__global__ __launch_bounds__(256) void gemm_qkv(
    const float* __restrict__ q, const float* __restrict__ k,
    const float* __restrict__ v, const float* __restrict__ wq,
    const float* __restrict__ wk, const float* __restrict__ wv,
    const float* __restrict__ bq, const float* __restrict__ bk,
    const float* __restrict__ bv,
    bf16* __restrict__ Yq, bf16* __restrict__ Yk, bf16* __restrict__ Vt)
{
  __shared__ __attribute__((aligned(16))) bf16 As[128 * 64];
  __shared__ __attribute__((aligned(16))) bf16 Bs[128 * 64];

  const int z = blockIdx.z;
  const float* A    = (z == 0) ? q  : (z == 1) ? k  : v;
  const float* Wz   = (z == 0) ? wq : (z == 1) ? wk : wv;
  const float* bias = (z == 0) ? bq : (z == 1) ? bk : bv;

  const int m0 = blockIdx.x * 128, n0 = blockIdx.y * 128;
  const int tid = threadIdx.x, wave = tid >> 6, lane = tid & 63;
  const int quad = lane >> 4, l16 = lane & 15;
  const int rw = wave >> 1, cw = wave & 1;
  const int swz = l16 & 7;

  f32x4 acc[4][4] = {};

  for (int k0 = 0; k0 < Dc; k0 += 64) {
    stage_f32_128x64(A  + (size_t)m0 * Dc + k0, Dc, As, tid);
    stage_f32_128x64(Wz + (size_t)n0 * Dc + k0, Dc, Bs, tid);
    __syncthreads();
#pragma unroll
    for (int ks = 0; ks < 2; ++ks) {
      bf16x8 af[4];
#pragma unroll
      for (int rt = 0; rt < 4; ++rt)
        af[rt] = *(const bf16x8*)
            &As[(rw * 64 + rt * 16 + l16) * 64 + (((ks * 4 + quad) ^ swz) * 8)];
#pragma unroll
      for (int ct = 0; ct < 4; ++ct) {
        bf16x8 bfr = *(const bf16x8*)
            &Bs[(cw * 64 + ct * 16 + l16) * 64 + (((ks * 4 + quad) ^ swz) * 8)];
#pragma unroll
        for (int rt = 0; rt < 4; ++rt)
          acc[rt][ct] = __builtin_amdgcn_mfma_f32_16x16x32_bf16(af[rt], bfr, acc[rt][ct], 0, 0, 0);
      }
    }
    __syncthreads();
  }

  if (z < 2) {
    bf16* Y = (z == 0) ? Yq : Yk;
#pragma unroll
    for (int ct = 0; ct < 4; ++ct) {
      const int col = n0 + cw * 64 + ct * 16 + l16;
      const float bvv = bias[col];
#pragma unroll
      for (int rt = 0; rt < 4; ++rt)
#pragma unroll
        for (int i = 0; i < 4; ++i) {
          const int row = m0 + rw * 64 + rt * 16 + quad * 4 + i;
          Y[(size_t)row * Dc + col] = (bf16)(acc[rt][ct][i] + bvv);
        }
    }
  } else {
    // V: write transposed -> Vt[(b*Dc + col)*Sc + s], i-axis contiguous
#pragma unroll
    for (int ct = 0; ct < 4; ++ct) {
      const int col = n0 + cw * 64 + ct * 16 + l16;
      const float bvv = bias[col];
#pragma unroll
      for (int rt = 0; rt < 4; ++rt) {
        const int row0 = m0 + rw * 64 + rt * 16 + quad * 4;  // multiple of 4
        const int bb = row0 >> 11, s0 = row0 & 2047;
        bf16x4 pk;
#pragma unroll
        for (int i = 0; i < 4; ++i) pk[i] = (bf16)(acc[rt][ct][i] + bvv);
        *(bf16x4*)&Vt[((size_t)bb * Dc + col) * Sc + s0] = pk;
      }
    }
  }
}

// ---------------------------------------------------------------------------
// O-projection GEMM: 128x128 tile, BK=64. A (bf16 attention output) staged via
// global_load_lds; B (wo, fp32) staged with in-staging conversion. fp32 out.
// ---------------------------------------------------------------------------
__global__ __launch_bounds__(256) void gemm_o(
    const bf16* __restrict__ A, const float* __restrict__ Wz,
    const float* __restrict__ bias, float* __restrict__ Y)
{
  __shared__ __attribute__((aligned(16))) bf16 As[128 * 64];
  __shared__ __attribute__((aligned(16))) bf16 Bs[128 * 64];

  const int m0 = blockIdx.x * 128, n0 = blockIdx.y * 128;
  const int tid = threadIdx.x, wave = tid >> 6, lane = tid & 63;
  const int quad = lane >> 4, l16 = lane & 15;
  const int rw = wave >> 1, cw = wave & 1;
  const int swz = l16 & 7;
  const int srow = wave * 8 + (lane >> 3);
  const int scol = ((lane & 7) ^ (lane >> 3)) * 8;

  f32x4 acc[4][4] = {};

  for (int k0 = 0; k0 < Dc; k0 += 64) {
#pragma unroll
    for (int s = 0; s < 4; ++s)
      gld_lds16(A + (size_t)(m0 + s * 32 + srow) * Dc + k0 + scol,
                &As[(s * 32 + wave * 8) * 64]);
    stage_f32_128x64(Wz + (size_t)n0 * Dc + k0, Dc, Bs, tid);
    __syncthreads();
#pragma unroll
    for (int ks = 0; ks < 2; ++ks) {
      bf16x8 af[4];
#pragma unroll
      for (int rt = 0; rt < 4; ++rt)
        af[rt] = *(const bf16x8*)
            &As[(rw * 64 + rt * 16 + l16) * 64 + (((ks * 4 + quad) ^ swz) * 8)];
#pragma unroll
      for (int ct = 0; ct < 4; ++ct) {
        bf16x8 bfr = *(const bf16x8*)
            &Bs[(cw * 64 + ct * 16 + l16) * 64 + (((ks * 4 + quad) ^ swz) * 8)];
#pragma unroll
        for (int rt = 0; rt < 4; ++rt)
          acc[rt][ct] = __builtin_amdgcn_mfma_f32_16x16x32_bf16(af[rt], bfr, acc[rt][ct], 0, 0, 0);
      }
    }
    __syncthreads();
  }

#pragma unroll
  for (int ct = 0; ct < 4; ++ct) {
    const int col = n0 + cw * 64 + ct * 16 + l16;
    const float bvv = bias[col];
#pragma unroll
    for (int rt = 0; rt < 4; ++rt)
#pragma unroll
      for (int i = 0; i < 4; ++i) {
        const int row = m0 + rw * 64 + rt * 16 + quad * 4 + i;
        Y[(size_t)row * Dc + col] = acc[rt][ct][i] + bvv;
      }
  }
}

// ---------------------------------------------------------------------------
// Fallback GEMM (fp32-staging 128x128, reg prefetch) for small workspaces.
// ---------------------------------------------------------------------------
template <bool AF32, bool BF32, bool OUTF32>
__global__ __launch_bounds__(256) void gemm128(
    const void* __restrict__ Av, const void* __restrict__ Bv,
    const float* __restrict__ bias, void* __restrict__ Yv,
    int M, int N, int K)
{
  __shared__ __attribute__((aligned(16))) bf16 As[2][128][40];
  __shared__ __attribute__((aligned(16))) bf16 Bs[2][128][40];

  const int m0 = blockIdx.x * 128, n0 = blockIdx.y * 128;
  const int tid = threadIdx.x, wave = tid >> 6, lane = tid & 63;
  const int quad = lane >> 4, l16 = lane & 15;
  const int rw = wave >> 1, cw = wave & 1;
  const int srow = tid >> 1, sc = (tid & 1) * 16;

  f32x4 acc[4][4] = {};

  auto load = [&](const void* P, bool f32, int r0, int k0, bf16x8& lo, bf16x8& hi) {
    if (f32) {
      const float* s = (const float*)P + (size_t)(r0 + srow) * K + k0 + sc;
      f32x4 a0 = ((const f32x4*)s)[0], a1 = ((const f32x4*)s)[1];
      f32x4 a2 = ((const f32x4*)s)[2], a3 = ((const f32x4*)s)[3];
      lo[0]=(bf16)a0[0]; lo[1]=(bf16)a0[1]; lo[2]=(bf16)a0[2]; lo[3]=(bf16)a0[3];
      lo[4]=(bf16)a1[0]; lo[5]=(bf16)a1[1]; lo[6]=(bf16)a1[2]; lo[7]=(bf16)a1[3];
      hi[0]=(bf16)a2[0]; hi[1]=(bf16)a2[1]; hi[2]=(bf16)a2[2]; hi[3]=(bf16)a2[3];
      hi[4]=(bf16)a3[0]; hi[5]=(bf16)a3[1]; hi[6]=(bf16)a3[2]; hi[7]=(bf16)a3[3];
    } else {
      const bf16* s = (const bf16*)P + (size_t)(r0 + srow) * K + k0 + sc;
      lo = ((const bf16x8*)s)[0]; hi = ((const bf16x8*)s)[1];
    }
  };

  bf16x8 alo, ahi, blo, bhi;
  load(Av, AF32, m0, 0, alo, ahi); load(Bv, BF32, n0, 0, blo, bhi);
  *(bf16x8*)&As[0][srow][sc] = alo; *(bf16x8*)&As[0][srow][sc + 8] = ahi;
  *(bf16x8*)&Bs[0][srow][sc] = blo; *(bf16x8*)&Bs[0][srow][sc + 8] = bhi;

  const int NIT = K >> 5;
  for (int it = 0; it < NIT; ++it) {
    __syncthreads();
    const int cur = it & 1;
    const bool pf = (it + 1) < NIT;
    if (pf) { load(Av, AF32, m0, (it+1)*32, alo, ahi); load(Bv, BF32, n0, (it+1)*32, blo, bhi); }

    bf16x8 af[4];
#pragma unroll
    for (int rt = 0; rt < 4; ++rt)
      af[rt] = *(const bf16x8*)&As[cur][rw * 64 + rt * 16 + l16][quad * 8];
#pragma unroll
    for (int ct = 0; ct < 4; ++ct) {
      bf16x8 bfr = *(const bf16x8*)&Bs[cur][cw * 64 + ct * 16 + l16][quad * 8];
#pragma unroll
      for (int rt = 0; rt < 4; ++rt)
        acc[rt][ct] = __builtin_amdgcn_mfma_f32_16x16x32_bf16(af[rt], bfr, acc[rt][ct], 0, 0, 0);
    }
    if (pf) {
      const int nxt = cur ^ 1;
      *(bf16x8*)&As[nxt][srow][sc] = alo; *(bf16x8*)&As[nxt][srow][sc + 8] = ahi;
      *(bf16x8*)&Bs[nxt][srow][sc] = blo; *(bf16x8*)&Bs[nxt][srow][sc + 8] = bhi;
    }
  }

#pragma unroll
  for (int ct = 0; ct < 4; ++ct) {
    const int col = n0 + cw * 64 + ct * 16 + l16;
    const float bvv = bias[col];
#pragma unroll
    for (int rt = 0; rt < 4; ++rt)
#pragma unroll
      for (int i = 0; i < 4; ++i) {
        const int row = m0 + rw * 64 + rt * 16 + quad * 4 + i;
        const float vv = acc[rt][ct][i] + bvv;
        if constexpr (OUTF32) ((float*)Yv)[(size_t)row * N + col] = vv;
        else                  ((bf16*)Yv)[(size_t)row * N + col] = (bf16)vv;
      }
  }
}

// ---------------------------------------------------------------------------
// Transpose V (fallback path only): (B*S, D) -> (B, D, S).
// ---------------------------------------------------------------------------
__global__ __launch_bounds__(256) void transpose_v(
    const bf16* __restrict__ in, bf16* __restrict__ out)
{
  __shared__ __attribute__((aligned(16))) bf16 tile[64][72];
  const int s0 = blockIdx.x * 64, d0 = blockIdx.y * 64, b = blockIdx.z;
  const int t = threadIdx.x, r = t >> 2, c = (t & 3) * 16;

  const bf16* src = in + (size_t)(b * Sc + s0 + r) * Dc + d0 + c;
  *(bf16x8*)&tile[r][c]     = ((const bf16x8*)src)[0];
  *(bf16x8*)&tile[r][c + 8] = ((const bf16x8*)src)[1];
  __syncthreads();

  bf16x8 t0, t1;
#pragma unroll
  for (int j = 0; j < 8; ++j) t0[j] = tile[c + j][r];
#pragma unroll
  for (int j = 0; j < 8; ++j) t1[j] = tile[c + 8 + j][r];
  bf16* dst = out + (size_t)(b * Dc + d0 + r) * Sc + s0 + c;
  ((bf16x8*)dst)[0] = t0;
  ((bf16x8*)dst)[1] = t1;
}

// ---------------------------------------------------------------------------
// Causal flash attention v5 (unchanged from R7 — occupancy-first, 6 blk/CU).
// ---------------------------------------------------------------------------
__global__ __launch_bounds__(256, 6) void attn5(
    const bf16* __restrict__ Q, const bf16* __restrict__ K,
    const bf16* __restrict__ Vt, bf16* __restrict__ O)
{
  __shared__ __attribute__((aligned(16))) bf16 Ks[64 * 64];
  __shared__ __attribute__((aligned(16))) bf16 Vs[64 * 64];   // [d][key]
  __shared__ __attribute__((aligned(16))) bf16 Ps[4][16][68]; // per-wave

  const int bh = blockIdx.x, b = bh >> 4, h = bh & 15;
  const int qy = blockIdx.y;
  const int qt = (qy & 8) ? ((qy & 24) | (7 - (qy & 7))) : qy;
  const int q0 = qt * 64;
  const int nkb = qt + 1;

  const int tid = threadIdx.x, wave = tid >> 6, lane = tid & 63;
  const int quad = lane >> 4, l16 = lane & 15;
  const int swz = l16 & 7;
  const int sr  = lane >> 3;                    // 0..7 row within 8-row group
  const int sgc = ((lane & 7) ^ sr) * 8;        // swizzled global chunk (elems)

  const bf16 onec = (bf16)1.0f;
  const bf16x8 ones = {onec, onec, onec, onec, onec, onec, onec, onec};

  const bf16* qrow = Q + (size_t)(b * Sc + q0 + wave * 16 + l16) * Dc + h * 64 + quad * 8;
  const bf16x8 aq0 = *(const bf16x8*)qrow;
  const bf16x8 aq1 = *(const bf16x8*)(qrow + 32);

  f32x4 oacc[4] = {{0,0,0,0},{0,0,0,0},{0,0,0,0},{0,0,0,0}};
  f32x4 lacc = {0, 0, 0, 0};

  for (int kb = 0; kb < nkb; ++kb) {
    __syncthreads();
#pragma unroll
    for (int j = 0; j < 2; ++j) {
      const int r = wave * 16 + j * 8 + sr;
      gld_lds16(K  + (size_t)(b * Sc + kb * 64 + r) * Dc + h * 64 + sgc,
                &Ks[(wave * 16 + j * 8) * 64]);
      gld_lds16(Vt + (size_t)(b * Dc + h * 64 + r) * Sc + kb * 64 + sgc,
                &Vs[(wave * 16 + j * 8) * 64]);
    }
    __syncthreads();

    // S^T = K * Q^T : A = K-frag (m=key), B = Q-frag (n=q)
    f32x4 s[4] = {{0,0,0,0},{0,0,0,0},{0,0,0,0},{0,0,0,0}};
#pragma unroll
    for (int d2 = 0; d2 < 2; ++d2) {
      const bf16x8 bq = d2 ? aq1 : aq0;
#pragma unroll
      for (int ct = 0; ct < 4; ++ct) {
        bf16x8 ak = *(const bf16x8*)
            &Ks[(ct * 16 + l16) * 64 + (((d2 * 4 + quad) ^ swz) * 8)];
        s[ct] = __builtin_amdgcn_mfma_f32_16x16x32_bf16(ak, bq, s[ct], 0, 0, 0);
      }
    }

    if (kb == nkb - 1) {
      const int qcol = wave * 16 + l16;
#pragma unroll
      for (int ct = 0; ct < 4; ++ct) {
        const int key0 = ct * 16 + quad * 4;
        bf16x4 pk;
#pragma unroll
        for (int i = 0; i < 4; ++i)
          pk[i] = (bf16)((key0 + i > qcol) ? 0.f : __expf(s[ct][i] * 0.125f));
        *(bf16x4*)&Ps[wave][l16][key0] = pk;
      }
    } else {
#pragma unroll
      for (int ct = 0; ct < 4; ++ct) {
        bf16x4 pk;
#pragma unroll
        for (int i = 0; i < 4; ++i) pk[i] = (bf16)__expf(s[ct][i] * 0.125f);
        *(bf16x4*)&Ps[wave][l16][ct * 16 + quad * 4] = pk;
      }
    }

    const bf16x8 ap0 = *(const bf16x8*)&Ps[wave][l16][quad * 8];
    const bf16x8 ap1 = *(const bf16x8*)&Ps[wave][l16][32 + quad * 8];

    lacc = __builtin_amdgcn_mfma_f32_16x16x32_bf16(ap0, ones, lacc, 0, 0, 0);
    lacc = __builtin_amdgcn_mfma_f32_16x16x32_bf16(ap1, ones, lacc, 0, 0, 0);

#pragma unroll
    for (int d2 = 0; d2 < 2; ++d2) {
      const bf16x8 ap = d2 ? ap1 : ap0;
#pragma unroll
      for (int ct = 0; ct < 4; ++ct) {
        bf16x8 bv = *(const bf16x8*)
            &Vs[(ct * 16 + l16) * 64 + (((d2 * 4 + quad) ^ swz) * 8)];
        oacc[ct] = __builtin_amdgcn_mfma_f32_16x16x32_bf16(ap, bv, oacc[ct], 0, 0, 0);
      }
    }
  }

  f32x4 rl;
#pragma unroll
  for (int i = 0; i < 4; ++i) rl[i] = 1.0f / lacc[i];
#pragma unroll
  for (int ct = 0; ct < 4; ++ct)
#pragma unroll
    for (int i = 0; i < 4; ++i)
      O[(size_t)(b * Sc + q0 + wave * 16 + quad * 4 + i) * Dc + h * 64 + ct * 16 + l16] =
          (bf16)(oacc[ct][i] * rl[i]);
}

// ---------------------------------------------------------------------------
extern "C" void kernel_launch(void* const* d_in, const int* in_sizes, int n_in,
                              void* d_out, int out_size, void* d_ws, size_t ws_size,
                              hipStream_t stream)
{
  const float* q  = (const float*)d_in[0];
  const float* k  = (const float*)d_in[1];
  const float* v  = (const float*)d_in[2];
  // d_in[3] = causal tril mask — deterministic, applied analytically
  const float* wq = (const float*)d_in[4];
  const float* bq = (const float*)d_in[5];
  const float* wk = (const float*)d_in[6];
  const float* bk = (const float*)d_in[7];
  const float* wv = (const float*)d_in[8];
  const float* bv = (const float*)d_in[9];
  const float* wo = (const float*)d_in[10];
  const float* bo = (const float*)d_in[11];
  float* out = (float*)d_out;

  constexpr size_t NQ = (size_t)Mtok * Dc;
  bf16* W = (bf16*)d_ws;
  const dim3 ga(Hc * Bc, 32);                // 1024 attn blocks
  const dim3 gt(Sc / 64, Dc / 64, Bc);

  const bool fancy = ws_size >= (size_t)(4 * NQ) * 2;  // 33.5 MB
  if (fancy) {
    bf16* Qp = W;
    bf16* Kp = W + NQ;
    bf16* Vt = W + 2 * NQ;
    bf16* AO = W + 3 * NQ;

    gemm_qkv<<<dim3(Mtok / 128, Dc / 128, 3), 256, 0, stream>>>(
        q, k, v, wq, wk, wv, bq, bk, bv, Qp, Kp, Vt);
    attn5<<<ga, 256, 0, stream>>>(Qp, Kp, Vt, AO);
    gemm_o<<<dim3(Mtok / 128, Dc / 128), 256, 0, stream>>>(AO, wo, bo, out);
  } else {
    // fallback: fp32 staging conversion inside the GEMMs, separate transpose
    bf16* Qp = W;
    bf16* Kp = W + NQ;
    bf16* Vp = W + 2 * NQ;
    bf16* Vt = W + 3 * NQ;
    bf16* AO = W + 4 * NQ;
    const dim3 gg(Mtok / 128, Dc / 128);
    gemm128<true, true, false><<<gg, 256, 0, stream>>>(q, wq, bq, Qp, Mtok, Dc, Dc);
    gemm128<true, true, false><<<gg, 256, 0, stream>>>(k, wk, bk, Kp, Mtok, Dc, Dc);
    gemm128<true, true, false><<<gg, 256, 0, stream>>>(v, wv, bv, Vp, Mtok, Dc, Dc);
    transpose_v<<<gt, 256, 0, stream>>>(Vp, Vt);
    attn5<<<ga, 256, 0, stream>>>(Qp, Kp, Vt, AO);
    gemm128<false, true, true><<<gg, 256, 0, stream>>>(AO, wo, bo, out, Mtok, Dc, Dc);
  }
}

// Round 9
// 215.974 us; speedup vs baseline: 1.1610x; 1.1610x over previous
//
#include <hip/hip_runtime.h>
#include <hip/hip_bf16.h>
#include <cstdint>

constexpr int Bc = 2, Sc = 2048, Dc = 1024, Hc = 16;
constexpr int Mtok = Bc * Sc;  // 4096 token rows

typedef __bf16 bf16;
typedef __bf16 bf16x4 __attribute__((ext_vector_type(4)));
typedef __bf16 bf16x8 __attribute__((ext_vector_type(8)));
typedef float  f32x4  __attribute__((ext_vector_type(4)));

// async global->LDS, 16B per lane; LDS dest = wave-uniform base + lane*16
__device__ __forceinline__ void gld_lds16(const bf16* g, bf16* l) {
  __builtin_amdgcn_global_load_lds(
      (__attribute__((address_space(1))) void*)(void*)g,
      (__attribute__((address_space(3))) void*)l, 16, 0, 0);
}

// ---------------------------------------------------------------------------
// One-time fp32 -> bf16 conversion of q,k,v and the 4 weight matrices.
// (R8 showed fp32-direct GEMM staging costs 2x fetch + exposed vmcnt; the
// separate convert kernel is ~14 us and keeps GEMMs on the async bf16 path.)
// ---------------------------------------------------------------------------
__global__ __launch_bounds__(256) void convert_all(
    const float* __restrict__ q, const float* __restrict__ k,
    const float* __restrict__ v, const float* __restrict__ wq,
    const float* __restrict__ wk, const float* __restrict__ wv,
    const float* __restrict__ wo, bf16* __restrict__ ws)
{
  constexpr size_t NQ = (size_t)Mtok * Dc;
  constexpr size_t NW = (size_t)Dc * Dc;
  const size_t e = ((size_t)blockIdx.x * 256 + threadIdx.x) * 8;
  const float* src; bf16* dst;
  if (e < 3 * NQ) {
    src = (e < NQ) ? q + e : (e < 2 * NQ) ? k + (e - NQ) : v + (e - 2 * NQ);
    dst = ws + e;
  } else {
    const size_t w = e - 3 * NQ;
    const float* wsrc = (w < NW) ? wq : (w < 2 * NW) ? wk : (w < 3 * NW) ? wv : wo;
    src = wsrc + (w & (NW - 1));
    dst = ws + 5 * NQ + w;
  }
  f32x4 a = ((const f32x4*)src)[0];
  f32x4 b = ((const f32x4*)src)[1];
  bf16x8 t;
  t[0]=(bf16)a[0]; t[1]=(bf16)a[1]; t[2]=(bf16)a[2]; t[3]=(bf16)a[3];
  t[4]=(bf16)b[0]; t[5]=(bf16)b[1]; t[6]=(bf16)b[2]; t[7]=(bf16)b[3];
  *(bf16x8*)dst = t;
}

// ---------------------------------------------------------------------------
// Fused Q/K/V projection GEMM: 64x128 tile, BK=64, XOR-swizzled LDS,
// global_load_lds width=16. grid (64,8,3) = 1536 blocks = 6 blocks/CU —
// doubles co-resident overlap vs the 128x128 version (R6-R8 showed the
// kernel is load-latency bound with phase-locked drains; overlap is the fix).
// LDS 24 KB; acc[4][2] keeps VGPR <= 85 for 6 waves/SIMD.
// z==2 (V) writes output TRANSPOSED to Vt (B, D, S) with packed 8B stores.
// ---------------------------------------------------------------------------
__global__ __launch_bounds__(256, 6) void gemm_qkv(
    const bf16* __restrict__ Aq, const bf16* __restrict__ Ak,
    const bf16* __restrict__ Av, const bf16* __restrict__ Wb,
    const float* __restrict__ bq, const float* __restrict__ bk,
    const float* __restrict__ bv,
    bf16* __restrict__ Yq, bf16* __restrict__ Yk, bf16* __restrict__ Vt)
{
  __shared__ __attribute__((aligned(16))) bf16 As[64 * 64];    // 8 KB
  __shared__ __attribute__((aligned(16))) bf16 Bs[128 * 64];   // 16 KB

  const int z = blockIdx.z;
  const bf16*  A    = (z == 0) ? Aq : (z == 1) ? Ak : Av;
  const bf16*  Wz   = Wb + (size_t)z * Dc * Dc;
  const float* bias = (z == 0) ? bq : (z == 1) ? bk : bv;

  const int m0 = blockIdx.x * 64, n0 = blockIdx.y * 128;
  const int tid = threadIdx.x, wave = tid >> 6, lane = tid & 63;
  const int quad = lane >> 4, l16 = lane & 15;
  const int swz = l16 & 7;
  const int sr  = lane >> 3;                       // 0..7
  const int scol = ((lane & 7) ^ sr) * 8;          // swizzled global chunk

  f32x4 acc[4][2] = {};

  for (int k0 = 0; k0 < Dc; k0 += 64) {
    // A: 64 rows, 2 instrs/wave (8 rows each)
#pragma unroll
    for (int j = 0; j < 2; ++j)
      gld_lds16(A + (size_t)(m0 + wave * 16 + j * 8 + sr) * Dc + k0 + scol,
                &As[(wave * 16 + j * 8) * 64]);
    // B: 128 rows, 4 instrs/wave
#pragma unroll
    for (int j = 0; j < 4; ++j)
      gld_lds16(Wz + (size_t)(n0 + wave * 32 + j * 8 + sr) * Dc + k0 + scol,
                &Bs[(wave * 32 + j * 8) * 64]);
    __syncthreads();
#pragma unroll
    for (int ks = 0; ks < 2; ++ks) {
      const int pc = ((ks * 4 + quad) ^ swz) * 8;
      bf16x8 af[4];
#pragma unroll
      for (int rt = 0; rt < 4; ++rt)
        af[rt] = *(const bf16x8*)&As[(rt * 16 + l16) * 64 + pc];
#pragma unroll
      for (int ct = 0; ct < 2; ++ct) {
        bf16x8 bfr = *(const bf16x8*)&Bs[(wave * 32 + ct * 16 + l16) * 64 + pc];
#pragma unroll
        for (int rt = 0; rt < 4; ++rt)
          acc[rt][ct] = __builtin_amdgcn_mfma_f32_16x16x32_bf16(af[rt], bfr, acc[rt][ct], 0, 0, 0);
      }
    }
    __syncthreads();
  }

  if (z < 2) {
    bf16* Y = (z == 0) ? Yq : Yk;
#pragma unroll
    for (int ct = 0; ct < 2; ++ct) {
      const int col = n0 + wave * 32 + ct * 16 + l16;
      const float bvv = bias[col];
#pragma unroll
      for (int rt = 0; rt < 4; ++rt)
#pragma unroll
        for (int i = 0; i < 4; ++i) {
          const int row = m0 + rt * 16 + quad * 4 + i;
          Y[(size_t)row * Dc + col] = (bf16)(acc[rt][ct][i] + bvv);
        }
    }
  } else {
    // V: write transposed -> Vt[(b*Dc + col)*Sc + s], i-axis contiguous
#pragma unroll
    for (int ct = 0; ct < 2; ++ct) {
      const int col = n0 + wave * 32 + ct * 16 + l16;
      const float bvv = bias[col];
#pragma unroll
      for (int rt = 0; rt < 4; ++rt) {
        const int row0 = m0 + rt * 16 + quad * 4;    // multiple of 4
        const int bb = row0 >> 11, s0 = row0 & 2047;
        bf16x4 pk;
#pragma unroll
        for (int i = 0; i < 4; ++i) pk[i] = (bf16)(acc[rt][ct][i] + bvv);
        *(bf16x4*)&Vt[((size_t)bb * Dc + col) * Sc + s0] = pk;
      }
    }
  }
}

// ---------------------------------------------------------------------------
// O-projection GEMM: 64x64 tile, BK=64, swizzled LDS, fp32 out.
// grid (64,16) = 1024 blocks = 4 blocks/CU (was 1/CU at 128x128 — the
// never-profiled straggler). LDS 16 KB.
// ---------------------------------------------------------------------------
__global__ __launch_bounds__(256, 4) void gemm_o(
    const bf16* __restrict__ A, const bf16* __restrict__ Wz,
    const float* __restrict__ bias, float* __restrict__ Y)
{
  __shared__ __attribute__((aligned(16))) bf16 As[64 * 64];
  __shared__ __attribute__((aligned(16))) bf16 Bs[64 * 64];

  const int m0 = blockIdx.x * 64, n0 = blockIdx.y * 64;
  const int tid = threadIdx.x, wave = tid >> 6, lane = tid & 63;
  const int quad = lane >> 4, l16 = lane & 15;
  const int swz = l16 & 7;
  const int sr  = lane >> 3;
  const int scol = ((lane & 7) ^ sr) * 8;

  f32x4 acc[4] = {};

  for (int k0 = 0; k0 < Dc; k0 += 64) {
#pragma unroll
    for (int j = 0; j < 2; ++j) {
      gld_lds16(A  + (size_t)(m0 + wave * 16 + j * 8 + sr) * Dc + k0 + scol,
                &As[(wave * 16 + j * 8) * 64]);
      gld_lds16(Wz + (size_t)(n0 + wave * 16 + j * 8 + sr) * Dc + k0 + scol,
                &Bs[(wave * 16 + j * 8) * 64]);
    }
    __syncthreads();
#pragma unroll
    for (int ks = 0; ks < 2; ++ks) {
      const int pc = ((ks * 4 + quad) ^ swz) * 8;
      bf16x8 bfr = *(const bf16x8*)&Bs[(wave * 16 + l16) * 64 + pc];
#pragma unroll
      for (int rt = 0; rt < 4; ++rt) {
        bf16x8 af = *(const bf16x8*)&As[(rt * 16 + l16) * 64 + pc];
        acc[rt] = __builtin_amdgcn_mfma_f32_16x16x32_bf16(af, bfr, acc[rt], 0, 0, 0);
      }
    }
    __syncthreads();
  }

  const int col = n0 + wave * 16 + l16;
  const float bvv = bias[col];
#pragma unroll
  for (int rt = 0; rt < 4; ++rt)
#pragma unroll
    for (int i = 0; i < 4; ++i) {
      const int row = m0 + rt * 16 + quad * 4 + i;
      Y[(size_t)row * Dc + col] = acc[rt][i] + bvv;
    }
}

// ---------------------------------------------------------------------------
// Fallback GEMM (fp32-staging 128x128, reg prefetch) for small workspaces.
// ---------------------------------------------------------------------------
template <bool AF32, bool BF32, bool OUTF32>
__global__ __launch_bounds__(256) void gemm128(
    const void* __restrict__ Av, const void* __restrict__ Bv,
    const float* __restrict__ bias, void* __restrict__ Yv,
    int M, int N, int K)
{
  __shared__ __attribute__((aligned(16))) bf16 As[2][128][40];
  __shared__ __attribute__((aligned(16))) bf16 Bs[2][128][40];

  const int m0 = blockIdx.x * 128, n0 = blockIdx.y * 128;
  const int tid = threadIdx.x, wave = tid >> 6, lane = tid & 63;
  const int quad = lane >> 4, l16 = lane & 15;
  const int rw = wave >> 1, cw = wave & 1;
  const int srow = tid >> 1, sc = (tid & 1) * 16;

  f32x4 acc[4][4] = {};

  auto load = [&](const void* P, bool f32, int r0, int k0, bf16x8& lo, bf16x8& hi) {
    if (f32) {
      const float* s = (const float*)P + (size_t)(r0 + srow) * K + k0 + sc;
      f32x4 a0 = ((const f32x4*)s)[0], a1 = ((const f32x4*)s)[1];
      f32x4 a2 = ((const f32x4*)s)[2], a3 = ((const f32x4*)s)[3];
      lo[0]=(bf16)a0[0]; lo[1]=(bf16)a0[1]; lo[2]=(bf16)a0[2]; lo[3]=(bf16)a0[3];
      lo[4]=(bf16)a1[0]; lo[5]=(bf16)a1[1]; lo[6]=(bf16)a1[2]; lo[7]=(bf16)a1[3];
      hi[0]=(bf16)a2[0]; hi[1]=(bf16)a2[1]; hi[2]=(bf16)a2[2]; hi[3]=(bf16)a2[3];
      hi[4]=(bf16)a3[0]; hi[5]=(bf16)a3[1]; hi[6]=(bf16)a3[2]; hi[7]=(bf16)a3[3];
    } else {
      const bf16* s = (const bf16*)P + (size_t)(r0 + srow) * K + k0 + sc;
      lo = ((const bf16x8*)s)[0]; hi = ((const bf16x8*)s)[1];
    }
  };

  bf16x8 alo, ahi, blo, bhi;
  load(Av, AF32, m0, 0, alo, ahi); load(Bv, BF32, n0, 0, blo, bhi);
  *(bf16x8*)&As[0][srow][sc] = alo; *(bf16x8*)&As[0][srow][sc + 8] = ahi;
  *(bf16x8*)&Bs[0][srow][sc] = blo; *(bf16x8*)&Bs[0][srow][sc + 8] = bhi;

  const int NIT = K >> 5;
  for (int it = 0; it < NIT; ++it) {
    __syncthreads();
    const int cur = it & 1;
    const bool pf = (it + 1) < NIT;
    if (pf) { load(Av, AF32, m0, (it+1)*32, alo, ahi); load(Bv, BF32, n0, (it+1)*32, blo, bhi); }

    bf16x8 af[4];
#pragma unroll
    for (int rt = 0; rt < 4; ++rt)
      af[rt] = *(const bf16x8*)&As[cur][rw * 64 + rt * 16 + l16][quad * 8];
#pragma unroll
    for (int ct = 0; ct < 4; ++ct) {
      bf16x8 bfr = *(const bf16x8*)&Bs[cur][cw * 64 + ct * 16 + l16][quad * 8];
#pragma unroll
      for (int rt = 0; rt < 4; ++rt)
        acc[rt][ct] = __builtin_amdgcn_mfma_f32_16x16x32_bf16(af[rt], bfr, acc[rt][ct], 0, 0, 0);
    }
    if (pf) {
      const int nxt = cur ^ 1;
      *(bf16x8*)&As[nxt][srow][sc] = alo; *(bf16x8*)&As[nxt][srow][sc + 8] = ahi;
      *(bf16x8*)&Bs[nxt][srow][sc] = blo; *(bf16x8*)&Bs[nxt][srow][sc + 8] = bhi;
    }
  }

#pragma unroll
  for (int ct = 0; ct < 4; ++ct) {
    const int col = n0 + cw * 64 + ct * 16 + l16;
    const float bvv = bias[col];
#pragma unroll
    for (int rt = 0; rt < 4; ++rt)
#pragma unroll
      for (int i = 0; i < 4; ++i) {
        const int row = m0 + rw * 64 + rt * 16 + quad * 4 + i;
        const float vv = acc[rt][ct][i] + bvv;
        if constexpr (OUTF32) ((float*)Yv)[(size_t)row * N + col] = vv;
        else                  ((bf16*)Yv)[(size_t)row * N + col] = (bf16)vv;
      }
  }
}

// ---------------------------------------------------------------------------
// Transpose V (fallback path only): (B*S, D) -> (B, D, S).
// ---------------------------------------------------------------------------
__global__ __launch_bounds__(256) void transpose_v(
    const bf16* __restrict__ in, bf16* __restrict__ out)
{
  __shared__ __attribute__((aligned(16))) bf16 tile[64][72];
  const int s0 = blockIdx.x * 64, d0 = blockIdx.y * 64, b = blockIdx.z;
  const int t = threadIdx.x, r = t >> 2, c = (t & 3) * 16;

  const bf16* src = in + (size_t)(b * Sc + s0 + r) * Dc + d0 + c;
  *(bf16x8*)&tile[r][c]     = ((const bf16x8*)src)[0];
  *(bf16x8*)&tile[r][c + 8] = ((const bf16x8*)src)[1];
  __syncthreads();

  bf16x8 t0, t1;
#pragma unroll
  for (int j = 0; j < 8; ++j) t0[j] = tile[c + j][r];
#pragma unroll
  for (int j = 0; j < 8; ++j) t1[j] = tile[c + 8 + j][r];
  bf16* dst = out + (size_t)(b * Dc + d0 + r) * Sc + s0 + c;
  ((bf16x8*)dst)[0] = t0;
  ((bf16x8*)dst)[1] = t1;
}

// ---------------------------------------------------------------------------
// Causal flash attention v5 (unchanged — occupancy-first, 6 blk/CU).
// ---------------------------------------------------------------------------
__global__ __launch_bounds__(256, 6) void attn5(
    const bf16* __restrict__ Q, const bf16* __restrict__ K,
    const bf16* __restrict__ Vt, bf16* __restrict__ O)
{
  __shared__ __attribute__((aligned(16))) bf16 Ks[64 * 64];
  __shared__ __attribute__((aligned(16))) bf16 Vs[64 * 64];   // [d][key]
  __shared__ __attribute__((aligned(16))) bf16 Ps[4][16][68]; // per-wave

  const int bh = blockIdx.x, b = bh >> 4, h = bh & 15;
  const int qy = blockIdx.y;
  const int qt = (qy & 8) ? ((qy & 24) | (7 - (qy & 7))) : qy;
  const int q0 = qt * 64;
  const int nkb = qt + 1;

  const int tid = threadIdx.x, wave = tid >> 6, lane = tid & 63;
  const int quad = lane >> 4, l16 = lane & 15;
  const int swz = l16 & 7;
  const int sr  = lane >> 3;
  const int sgc = ((lane & 7) ^ sr) * 8;

  const bf16 onec = (bf16)1.0f;
  const bf16x8 ones = {onec, onec, onec, onec, onec, onec, onec, onec};

  const bf16* qrow = Q + (size_t)(b * Sc + q0 + wave * 16 + l16) * Dc + h * 64 + quad * 8;
  const bf16x8 aq0 = *(const bf16x8*)qrow;
  const bf16x8 aq1 = *(const bf16x8*)(qrow + 32);

  f32x4 oacc[4] = {{0,0,0,0},{0,0,0,0},{0,0,0,0},{0,0,0,0}};
  f32x4 lacc = {0, 0, 0, 0};

  for (int kb = 0; kb < nkb; ++kb) {
    __syncthreads();
#pragma unroll
    for (int j = 0; j < 2; ++j) {
      const int r = wave * 16 + j * 8 + sr;
      gld_lds16(K  + (size_t)(b * Sc + kb * 64 + r) * Dc + h * 64 + sgc,
                &Ks[(wave * 16 + j * 8) * 64]);
      gld_lds16(Vt + (size_t)(b * Dc + h * 64 + r) * Sc + kb * 64 + sgc,
                &Vs[(wave * 16 + j * 8) * 64]);
    }
    __syncthreads();

    // S^T = K * Q^T : A = K-frag (m=key), B = Q-frag (n=q)
    f32x4 s[4] = {{0,0,0,0},{0,0,0,0},{0,0,0,0},{0,0,0,0}};
#pragma unroll
    for (int d2 = 0; d2 < 2; ++d2) {
      const bf16x8 bq = d2 ? aq1 : aq0;
#pragma unroll
      for (int ct = 0; ct < 4; ++ct) {
        bf16x8 ak = *(const bf16x8*)
            &Ks[(ct * 16 + l16) * 64 + (((d2 * 4 + quad) ^ swz) * 8)];
        s[ct] = __builtin_amdgcn_mfma_f32_16x16x32_bf16(ak, bq, s[ct], 0, 0, 0);
      }
    }

    if (kb == nkb - 1) {
      const int qcol = wave * 16 + l16;
#pragma unroll
      for (int ct = 0; ct < 4; ++ct) {
        const int key0 = ct * 16 + quad * 4;
        bf16x4 pk;
#pragma unroll
        for (int i = 0; i < 4; ++i)
          pk[i] = (bf16)((key0 + i > qcol) ? 0.f : __expf(s[ct][i] * 0.125f));
        *(bf16x4*)&Ps[wave][l16][key0] = pk;
      }
    } else {
#pragma unroll
      for (int ct = 0; ct < 4; ++ct) {
        bf16x4 pk;
#pragma unroll
        for (int i = 0; i < 4; ++i) pk[i] = (bf16)__expf(s[ct][i] * 0.125f);
        *(bf16x4*)&Ps[wave][l16][ct * 16 + quad * 4] = pk;
      }
    }

    const bf16x8 ap0 = *(const bf16x8*)&Ps[wave][l16][quad * 8];
    const bf16x8 ap1 = *(const bf16x8*)&Ps[wave][l16][32 + quad * 8];

    lacc = __builtin_amdgcn_mfma_f32_16x16x32_bf16(ap0, ones, lacc, 0, 0, 0);
    lacc = __builtin_amdgcn_mfma_f32_16x16x32_bf16(ap1, ones, lacc, 0, 0, 0);

#pragma unroll
    for (int d2 = 0; d2 < 2; ++d2) {
      const bf16x8 ap = d2 ? ap1 : ap0;
#pragma unroll
      for (int ct = 0; ct < 4; ++ct) {
        bf16x8 bv = *(const bf16x8*)
            &Vs[(ct * 16 + l16) * 64 + (((d2 * 4 + quad) ^ swz) * 8)];
        oacc[ct] = __builtin_amdgcn_mfma_f32_16x16x32_bf16(ap, bv, oacc[ct], 0, 0, 0);
      }
    }
  }

  f32x4 rl;
#pragma unroll
  for (int i = 0; i < 4; ++i) rl[i] = 1.0f / lacc[i];
#pragma unroll
  for (int ct = 0; ct < 4; ++ct)
#pragma unroll
    for (int i = 0; i < 4; ++i)
      O[(size_t)(b * Sc + q0 + wave * 16 + quad * 4 + i) * Dc + h * 64 + ct * 16 + l16] =
          (bf16)(oacc[ct][i] * rl[i]);
}

// ---------------------------------------------------------------------------
extern "C" void kernel_launch(void* const* d_in, const int* in_sizes, int n_in,
                              void* d_out, int out_size, void* d_ws, size_t ws_size,
                              hipStream_t stream)
{
  const float* q  = (const float*)d_in[0];
  const float* k  = (const float*)d_in[1];
  const float* v  = (const float*)d_in[2];
  // d_in[3] = causal tril mask — deterministic, applied analytically
  const float* wq = (const float*)d_in[4];
  const float* bq = (const float*)d_in[5];
  const float* wk = (const float*)d_in[6];
  const float* bk = (const float*)d_in[7];
  const float* wv = (const float*)d_in[8];
  const float* bv = (const float*)d_in[9];
  const float* wo = (const float*)d_in[10];
  const float* bo = (const float*)d_in[11];
  float* out = (float*)d_out;

  constexpr size_t NQ = (size_t)Mtok * Dc;
  constexpr size_t NW = (size_t)Dc * Dc;
  bf16* W = (bf16*)d_ws;
  const dim3 ga(Hc * Bc, 32);                // 1024 attn blocks
  const dim3 gt(Sc / 64, Dc / 64, Bc);

  const bool fancy = ws_size >= (size_t)(6 * NQ + 4 * NW) * 2;  // 58.7 MB
  if (fancy) {
    bf16* xq = W;             // dead after gemm_qkv -> reused as AO
    bf16* xk = W + NQ;
    bf16* xv = W + 2 * NQ;
    bf16* Qp = W + 3 * NQ;
    bf16* Kp = W + 4 * NQ;
    bf16* wb = W + 5 * NQ;    // wq,wk,wv,wo bf16 (4*NW)
    bf16* Vt = W + 5 * NQ + 4 * NW;  // fresh region
    bf16* AO = W;             // reuse xq

    convert_all<<<8192, 256, 0, stream>>>(q, k, v, wq, wk, wv, wo, W);
    gemm_qkv<<<dim3(Mtok / 64, Dc / 128, 3), 256, 0, stream>>>(
        xq, xk, xv, wb, bq, bk, bv, Qp, Kp, Vt);
    attn5<<<ga, 256, 0, stream>>>(Qp, Kp, Vt, AO);
    gemm_o<<<dim3(Mtok / 64, Dc / 64), 256, 0, stream>>>(AO, wb + 3 * NW, bo, out);
  } else {
    // fallback: fp32 staging conversion inside the GEMMs, separate transpose
    bf16* Qp = W;
    bf16* Kp = W + NQ;
    bf16* Vp = W + 2 * NQ;
    bf16* Vt = W + 3 * NQ;
    bf16* AO = W + 4 * NQ;
    const dim3 gg(Mtok / 128, Dc / 128);
    gemm128<true, true, false><<<gg, 256, 0, stream>>>(q, wq, bq, Qp, Mtok, Dc, Dc);
    gemm128<true, true, false><<<gg, 256, 0, stream>>>(k, wk, bk, Kp, Mtok, Dc, Dc);
    gemm128<true, true, false><<<gg, 256, 0, stream>>>(v, wv, bv, Vp, Mtok, Dc, Dc);
    transpose_v<<<gt, 256, 0, stream>>>(Vp, Vt);
    attn5<<<ga, 256, 0, stream>>>(Qp, Kp, Vt, AO);
    gemm128<false, true, true><<<gg, 256, 0, stream>>>(AO, wo, bo, out, Mtok, Dc, Dc);
  }
}